// Round 4
// baseline (2243.486 us; speedup 1.0000x reference)
//
#include <hip/hip_runtime.h>

// MultiHeadAttention fp32 for MI355X (gfx950).
// B=4, S=2048, D_MODEL=768, H=12, DK=64.
// d_out = [out (4*2048*768)] ++ [attn_weights (4*12*2048*2048)], fp32.
// Workspace layout (floats): Qh | Kh | Vh (each [B,H,S,64]) | AO [B,S,768] | rowsum [B,H,S]
//   -> needs 25,264,128 floats = 101.1 MB of d_ws.
//
// R4 = R2 resubmitted verbatim (R2, R3 both hit GPUAcquisitionTimeout; the
// kernel has never run). Changes vs R1 (2023 us):
//  - av_kernel v3: inner loop was LDS-BW-bound (acc 4x4 = 2 B/FMA vs 1 B/FMA
//    balance point; es rows 8 apart aliased to the same banks -> 4-way
//    conflict). Now 128 threads, 128q x 64d tile, acc[8][8] (1 B/FMA),
//    XOR-swizzled es columns (conflict-free), reg-prefetch kept.
//  - out-proj GEMM: was 384 blocks = 1.5 blocks/CU (half the CUs idle).
//    Now 64x128 tiles -> 768 blocks (3/CU), acc[4][8], reg-prefetch.
//  - scores/qkv unchanged (occupancy already adequate).

#define D_MODEL 768
#define NH 12
#define DK 64
#define BATCH 4
#define SEQ 2048
#define BS (BATCH * SEQ)          // 8192 rows
#define HEADS_TOTAL (BATCH * NH)  // 48

// ---------------------------------------------------------------------------
// Fused Q/K/V projection (blockIdx.z selects operand set). 128x128 tile,
// 256 threads, 8x8 acc, BK=16. Scatters into head-split layout [B][H][S][DK].
// ---------------------------------------------------------------------------
__global__ __launch_bounds__(256)
void qkv_gemm_kernel(const float* __restrict__ Aq, const float* __restrict__ Ak,
                     const float* __restrict__ Av,
                     const float* __restrict__ Wq, const float* __restrict__ Wk,
                     const float* __restrict__ Wv,
                     const float* __restrict__ bq, const float* __restrict__ bk,
                     const float* __restrict__ bv,
                     float* __restrict__ Cq, float* __restrict__ Ck,
                     float* __restrict__ Cv)
{
    const float* A; const float* W; const float* bias; float* C;
    if (blockIdx.z == 0)      { A = Aq; W = Wq; bias = bq; C = Cq; }
    else if (blockIdx.z == 1) { A = Ak; W = Wk; bias = bk; C = Ck; }
    else                      { A = Av; W = Wv; bias = bv; C = Cv; }

    __shared__ float As[16][136];
    __shared__ float Bs[16][136];
    const int t  = threadIdx.x;
    const int tx = t & 15, ty = t >> 4;
    const int m0 = blockIdx.y * 128;
    const int n0 = blockIdx.x * 128;

    float acc[8][8];
#pragma unroll
    for (int i = 0; i < 8; ++i)
#pragma unroll
        for (int j = 0; j < 8; ++j) acc[i][j] = 0.f;

    for (int kt = 0; kt < D_MODEL; kt += 16) {
#pragma unroll
        for (int i = 0; i < 2; ++i) {
            int L = t + i * 256;
            int m = L >> 2, kq = (L & 3) * 4;
            float4 v = *(const float4*)(A + (size_t)(m0 + m) * D_MODEL + kt + kq);
            As[kq + 0][m] = v.x; As[kq + 1][m] = v.y;
            As[kq + 2][m] = v.z; As[kq + 3][m] = v.w;
        }
#pragma unroll
        for (int i = 0; i < 2; ++i) {
            int L = t + i * 256;
            int kk = L >> 5, nq = (L & 31) * 4;
            *(float4*)&Bs[kk][nq] = *(const float4*)(W + (size_t)(kt + kk) * D_MODEL + n0 + nq);
        }
        __syncthreads();
#pragma unroll
        for (int kk = 0; kk < 16; ++kk) {
            float a[8], b[8];
            *(float4*)&a[0] = *(float4*)&As[kk][ty * 8];
            *(float4*)&a[4] = *(float4*)&As[kk][ty * 8 + 4];
            *(float4*)&b[0] = *(float4*)&Bs[kk][tx * 8];
            *(float4*)&b[4] = *(float4*)&Bs[kk][tx * 8 + 4];
#pragma unroll
            for (int i = 0; i < 8; ++i)
#pragma unroll
                for (int j = 0; j < 8; ++j)
                    acc[i][j] += a[i] * b[j];
        }
        __syncthreads();
    }

    float bvv[8];
    *(float4*)&bvv[0] = *(const float4*)(bias + n0 + tx * 8);
    *(float4*)&bvv[4] = *(const float4*)(bias + n0 + tx * 8 + 4);

#pragma unroll
    for (int i = 0; i < 8; ++i) {
        int m = m0 + ty * 8 + i;
        float o[8];
#pragma unroll
        for (int j = 0; j < 8; ++j) o[j] = acc[i][j] + bvv[j];
        int n = n0 + tx * 8;
        int b = m >> 11, s = m & 2047, h = n >> 6, d = n & 63;
        float* dst = C + (((size_t)(b * NH + h)) << 17) + ((size_t)s << 6) + d;
        *(float4*)dst       = make_float4(o[0], o[1], o[2], o[3]);
        *(float4*)(dst + 4) = make_float4(o[4], o[5], o[6], o[7]);
    }
}

// ---------------------------------------------------------------------------
// Scores: per (b,h), tile of 128 q x 128 keys. s = (Q . K)/8, e = exp(s).
// Writes UNNORMALIZED e to attn area; atomicAdd per-row sums of e.
// (12288 blocks -> machine already filled; unchanged.)
// ---------------------------------------------------------------------------
__global__ __launch_bounds__(256)
void scores_kernel(const float* __restrict__ Qh, const float* __restrict__ Kh,
                   float* __restrict__ attn, float* __restrict__ rowsum)
{
    __shared__ float Qs[32][132];  // transposed: Qs[kd][q]
    __shared__ float Ks[32][132];  // transposed: Ks[kd][n]
    const int t  = threadIdx.x;
    const int tx = t & 15, ty = t >> 4;
    const int bh = blockIdx.z;
    const int q0 = blockIdx.y * 128;
    const int n0 = blockIdx.x * 128;
    const float* Q  = Qh + ((size_t)bh << 17);
    const float* Kp = Kh + ((size_t)bh << 17);
    float* attnBH   = attn + ((size_t)bh << 22);

    float acc[8][8];
#pragma unroll
    for (int i = 0; i < 8; ++i)
#pragma unroll
        for (int j = 0; j < 8; ++j) acc[i][j] = 0.f;

    for (int kt = 0; kt < DK; kt += 32) {
#pragma unroll
        for (int i = 0; i < 4; ++i) {
            int L = t + i * 256;
            int r = L >> 3, c4 = (L & 7) * 4;
            float4 v = *(const float4*)(Q  + (size_t)(q0 + r) * DK + kt + c4);
            Qs[c4 + 0][r] = v.x; Qs[c4 + 1][r] = v.y;
            Qs[c4 + 2][r] = v.z; Qs[c4 + 3][r] = v.w;
            float4 w = *(const float4*)(Kp + (size_t)(n0 + r) * DK + kt + c4);
            Ks[c4 + 0][r] = w.x; Ks[c4 + 1][r] = w.y;
            Ks[c4 + 2][r] = w.z; Ks[c4 + 3][r] = w.w;
        }
        __syncthreads();
#pragma unroll
        for (int kk = 0; kk < 32; ++kk) {
            float a[8], b[8];
            *(float4*)&a[0] = *(float4*)&Qs[kk][ty * 8];
            *(float4*)&a[4] = *(float4*)&Qs[kk][ty * 8 + 4];
            *(float4*)&b[0] = *(float4*)&Ks[kk][tx * 8];
            *(float4*)&b[4] = *(float4*)&Ks[kk][tx * 8 + 4];
#pragma unroll
            for (int i = 0; i < 8; ++i)
#pragma unroll
                for (int j = 0; j < 8; ++j)
                    acc[i][j] += a[i] * b[j];
        }
        __syncthreads();
    }

    float rs[8];
#pragma unroll
    for (int i = 0; i < 8; ++i) {
        float r = 0.f;
#pragma unroll
        for (int j = 0; j < 8; ++j) {
            float e = __expf(acc[i][j] * 0.125f);
            acc[i][j] = e;
            r += e;
        }
        rs[i] = r;
        float* dst = attnBH + (size_t)(q0 + ty * 8 + i) * SEQ + n0 + tx * 8;
        *(float4*)dst       = make_float4(acc[i][0], acc[i][1], acc[i][2], acc[i][3]);
        *(float4*)(dst + 4) = make_float4(acc[i][4], acc[i][5], acc[i][6], acc[i][7]);
    }
#pragma unroll
    for (int i = 0; i < 8; ++i) {
        float r = rs[i];
        r += __shfl_xor(r, 1, 16);
        r += __shfl_xor(r, 2, 16);
        r += __shfl_xor(r, 4, 16);
        r += __shfl_xor(r, 8, 16);
        if (tx == 0)
            atomicAdd(rowsum + (size_t)bh * SEQ + q0 + ty * 8 + i, r);
    }
}

// ---------------------------------------------------------------------------
// AV v3: AO[q][d] = (sum_k e[q][k] * V[k][d]) / rowsum[q]; rewrites attn
// in-place as normalized weights.
// 128 threads, 128q x 64d tile, acc[8][8] -> 1 B LDS per FMA (balanced with
// the 128 B/cyc/CU LDS peak; the old 4x4 was 2 B/FMA = LDS-bound at 50%).
// es columns XOR-swizzled: rows 8 apart alias to the same banks at stride 36
// (8*36 % 32 == 0); col ^ ((row>>3)&7)<<2 makes the 8-row read fan
// conflict-free while float4 granularity is preserved.
// ---------------------------------------------------------------------------
#define AV_SWZ(r, c) ((c) ^ ((((r) >> 3) & 7) << 2))

__global__ __launch_bounds__(128)
void av_kernel(const float* __restrict__ Vh, float* __restrict__ attn,
               const float* __restrict__ rowsum, float* __restrict__ AO)
{
    __shared__ float es[128][36];  // e tile [q][k-chunk 32], swizzled cols
    __shared__ float Vs[32][72];   // V tile [k][d]
    __shared__ float rsl[128];
    const int t  = threadIdx.x;    // 0..127
    const int tx = t & 7;          // d = tx*8 + j
    const int ty = t >> 3;         // q = ty*8 + i
    const int bh = blockIdx.y;
    const int q0 = blockIdx.x * 128;
    const float* V = Vh + ((size_t)bh << 17);
    float* attnBH  = attn + ((size_t)bh << 22);

    rsl[t] = 1.0f / rowsum[(size_t)bh * SEQ + q0 + t];

    // staging geometry: es: 8 float4/thread at rows er0+16i, col ec;
    //                   Vs: 4 float4/thread at rows vr0+8i, col vc.
    const int er0 = t >> 3;          // 0..15
    const int ec  = (t & 7) * 4;     // 0..28
    const int vr0 = t >> 4;          // 0..7
    const int vc  = (t & 15) * 4;    // 0..60

    float* pA       = attnBH + (size_t)(q0 + er0) * SEQ + ec;  // + i*16*SEQ + kt
    const float* pV = V + (size_t)vr0 * DK + vc;               // + (kt + 8i)*DK

    // prefetch chunk 0
    float4 pe[8], pv[4];
#pragma unroll
    for (int i = 0; i < 8; ++i) pe[i] = *(const float4*)(pA + (size_t)i * 16 * SEQ);
#pragma unroll
    for (int i = 0; i < 4; ++i) pv[i] = *(const float4*)(pV + (size_t)(8 * i) * DK);

    float acc[8][8] = {};

    __syncthreads();  // rsl visible
    float rinv_st[8];
#pragma unroll
    for (int i = 0; i < 8; ++i) rinv_st[i] = rsl[er0 + 16 * i];

    for (int kt = 0; kt < SEQ; kt += 32) {
        // stage current chunk regs -> LDS (es col-swizzled)
#pragma unroll
        for (int i = 0; i < 8; ++i) {
            int r = er0 + 16 * i;
            *(float4*)&es[r][AV_SWZ(r, ec)] = pe[i];
        }
#pragma unroll
        for (int i = 0; i < 4; ++i)
            *(float4*)&Vs[vr0 + 8 * i][vc] = pv[i];
        __syncthreads();

        // normalized attn write-back (stores drain during compute)
#pragma unroll
        for (int i = 0; i < 8; ++i) {
            float r = rinv_st[i];
            *(float4*)(pA + (size_t)i * 16 * SEQ + kt) =
                make_float4(pe[i].x * r, pe[i].y * r, pe[i].z * r, pe[i].w * r);
        }
        // issue next chunk's loads; latency hides under the 2048-FMA phase
        if (kt + 32 < SEQ) {
#pragma unroll
            for (int i = 0; i < 8; ++i)
                pe[i] = *(const float4*)(pA + (size_t)i * 16 * SEQ + kt + 32);
#pragma unroll
            for (int i = 0; i < 4; ++i)
                pv[i] = *(const float4*)(pV + (size_t)(kt + 32 + 8 * i) * DK);
        }

#pragma unroll
        for (int kk = 0; kk < 32; kk += 4) {
            float vb[4][8];
#pragma unroll
            for (int kb = 0; kb < 4; ++kb) {
                float4 v0 = *(float4*)&Vs[kk + kb][tx * 8];
                float4 v1 = *(float4*)&Vs[kk + kb][tx * 8 + 4];
                vb[kb][0] = v0.x; vb[kb][1] = v0.y; vb[kb][2] = v0.z; vb[kb][3] = v0.w;
                vb[kb][4] = v1.x; vb[kb][5] = v1.y; vb[kb][6] = v1.z; vb[kb][7] = v1.w;
            }
#pragma unroll
            for (int i = 0; i < 8; ++i) {
                int r = ty * 8 + i;
                float4 e = *(float4*)&es[r][AV_SWZ(r, kk)];
                float ev[4] = {e.x, e.y, e.z, e.w};
#pragma unroll
                for (int kb = 0; kb < 4; ++kb)
#pragma unroll
                    for (int j = 0; j < 8; ++j)
                        acc[i][j] += ev[kb] * vb[kb][j];
            }
        }
        __syncthreads();
    }

    const int b = bh / NH, h = bh % NH;
#pragma unroll
    for (int i = 0; i < 8; ++i) {
        const int q = q0 + ty * 8 + i;
        const float rr = rsl[ty * 8 + i];
        float* dst = AO + (size_t)(b * SEQ + q) * D_MODEL + h * DK + tx * 8;
        *(float4*)dst = make_float4(acc[i][0] * rr, acc[i][1] * rr,
                                    acc[i][2] * rr, acc[i][3] * rr);
        *(float4*)(dst + 4) = make_float4(acc[i][4] * rr, acc[i][5] * rr,
                                          acc[i][6] * rr, acc[i][7] * rr);
    }
}

// ---------------------------------------------------------------------------
// Output projection GEMM: C[M][768] = A[M][768] @ W + bias.
// 64x128 tiles -> grid (6,128) = 768 blocks (3/CU vs the old 1.5/CU),
// 256 threads, acc[4][8], BK=16, register prefetch of the next K-slab.
// ---------------------------------------------------------------------------
__global__ __launch_bounds__(256)
void out_gemm_kernel(const float* __restrict__ A, const float* __restrict__ W,
                     const float* __restrict__ bias, float* __restrict__ C)
{
    __shared__ float As[16][68];   // transposed A tile: As[k][m], 64 m
    __shared__ float Bs[16][136];  // Bs[k][n], 128 n
    const int t  = threadIdx.x;
    const int tx = t & 15, ty = t >> 4;
    const int m0 = blockIdx.y * 64;
    const int n0 = blockIdx.x * 128;

    // staging geometry: A: 1 float4/thread; B: 2 float4/thread
    const int am = t >> 2, akq = (t & 3) * 4;
    const int bk0 = t >> 5,         bn0 = (t & 31) * 4;
    const int bk1 = (t + 256) >> 5, bn1 = bn0;

    const float* pA = A + (size_t)(m0 + am) * D_MODEL + akq;
    const float* pB = W + n0;

    float4 pa  = *(const float4*)pA;
    float4 pb0 = *(const float4*)(pB + (size_t)bk0 * D_MODEL + bn0);
    float4 pb1 = *(const float4*)(pB + (size_t)bk1 * D_MODEL + bn1);

    float acc[4][8] = {};

    for (int kt = 0; kt < D_MODEL; kt += 16) {
        As[akq + 0][am] = pa.x; As[akq + 1][am] = pa.y;
        As[akq + 2][am] = pa.z; As[akq + 3][am] = pa.w;
        *(float4*)&Bs[bk0][bn0] = pb0;
        *(float4*)&Bs[bk1][bn1] = pb1;
        __syncthreads();

        if (kt + 16 < D_MODEL) {
            pa  = *(const float4*)(pA + kt + 16);
            pb0 = *(const float4*)(pB + (size_t)(kt + 16 + bk0) * D_MODEL + bn0);
            pb1 = *(const float4*)(pB + (size_t)(kt + 16 + bk1) * D_MODEL + bn1);
        }

#pragma unroll
        for (int kk = 0; kk < 16; ++kk) {
            float4 a = *(float4*)&As[kk][ty * 4];
            float b[8];
            *(float4*)&b[0] = *(float4*)&Bs[kk][tx * 8];
            *(float4*)&b[4] = *(float4*)&Bs[kk][tx * 8 + 4];
            float av[4] = {a.x, a.y, a.z, a.w};
#pragma unroll
            for (int i = 0; i < 4; ++i)
#pragma unroll
                for (int j = 0; j < 8; ++j)
                    acc[i][j] += av[i] * b[j];
        }
        __syncthreads();
    }

    float bv[8];
    *(float4*)&bv[0] = *(const float4*)(bias + n0 + tx * 8);
    *(float4*)&bv[4] = *(const float4*)(bias + n0 + tx * 8 + 4);

#pragma unroll
    for (int i = 0; i < 4; ++i) {
        int m = m0 + ty * 4 + i;
        float* dst = C + (size_t)m * D_MODEL + n0 + tx * 8;
        *(float4*)dst       = make_float4(acc[i][0] + bv[0], acc[i][1] + bv[1],
                                          acc[i][2] + bv[2], acc[i][3] + bv[3]);
        *(float4*)(dst + 4) = make_float4(acc[i][4] + bv[4], acc[i][5] + bv[5],
                                          acc[i][6] + bv[6], acc[i][7] + bv[7]);
    }
}

// ---------------------------------------------------------------------------
extern "C" void kernel_launch(void* const* d_in, const int* in_sizes, int n_in,
                              void* d_out, int out_size, void* d_ws, size_t ws_size,
                              hipStream_t stream)
{
    const float* q   = (const float*)d_in[0];
    const float* k   = (const float*)d_in[1];
    const float* v   = (const float*)d_in[2];
    const float* Wq  = (const float*)d_in[3];
    const float* bq  = (const float*)d_in[4];
    const float* Wk  = (const float*)d_in[5];
    const float* bk  = (const float*)d_in[6];
    const float* Wv  = (const float*)d_in[7];
    const float* bv  = (const float*)d_in[8];
    const float* Wo  = (const float*)d_in[9];
    const float* bo  = (const float*)d_in[10];

    float* out  = (float*)d_out;
    float* attn = out + (size_t)BS * D_MODEL;

    const size_t HSZ = (size_t)HEADS_TOTAL * SEQ * DK;
    float* ws     = (float*)d_ws;
    float* Qh     = ws;
    float* Kh     = ws + HSZ;
    float* Vh     = ws + 2 * HSZ;
    float* AO     = ws + 3 * HSZ;
    float* rowsum = ws + 4 * HSZ;

    hipMemsetAsync(rowsum, 0, (size_t)HEADS_TOTAL * SEQ * sizeof(float), stream);

    dim3 gQKV(D_MODEL / 128, BS / 128, 3);  // 1152 blocks
    qkv_gemm_kernel<<<gQKV, 256, 0, stream>>>(q, k, v, Wq, Wk, Wv,
                                              bq, bk, bv, Qh, Kh, Vh);

    scores_kernel<<<dim3(SEQ / 128, SEQ / 128, HEADS_TOTAL), 256, 0, stream>>>(Qh, Kh, attn, rowsum);

    av_kernel<<<dim3(SEQ / 128, HEADS_TOTAL), 128, 0, stream>>>(Vh, attn, rowsum, AO);

    out_gemm_kernel<<<dim3(D_MODEL / 128, BS / 64), 256, 0, stream>>>(AO, Wo, bo, out);
}